// Round 12
// baseline (530.238 us; speedup 1.0000x reference)
//
#include <hip/hip_runtime.h>

// Single-query cross-attention, algebraically collapsed:
//   scores[h,l] = (scale*Wk_h^T q_h) . x[l]      (k-bias cancels in softmax)
//   out_attn[h] = Wv_h @ (sum_l softmax_w[l] * x[l]) + bv_h
// => one streaming pass over x (64 MB), memory-bound.
// R12: ALL phases fused into ONE kernel (q -> qk -> main -> vproj -> oproj)
// with manual grid barriers (monotonic atomic counter + s_sleep spin).
// 1024 blocks x 256 thr, launch_bounds(256,4): VGPR<=128 + 16.5KB LDS
// -> 4 blocks/CU statically guaranteed -> all blocks co-resident, no deadlock.
// Cross-phase data written via atomics (coherent point) and read cold after
// the barrier -> no cross-XCD stale-cache hazard. P2 = reverted R9 single-pass
// main loop (R10 two-phase regressed 118->123.7).
// k_init zeros counter + accumulators (2 launches total, both plain -> capture-safe).

#define DIM   512
#define NH    4
#define HDIM  128
#define SCALE 0.08838834764831845f  // 1/sqrt(128)

#define NBLK           1024
#define ROWS_PER_TILE  32
#define ROWS_PER_WAVE  8
#define NSLOT          32

// ws layout (float offsets). Total (3264+65536)*4 ~ 275 KB.
#define WS_Q     0      // 512
#define WS_QKS   512    // 2048
#define WS_ATTN  2560   // 512
#define WS_S     3072   // NSLOT*NH = 128
#define WS_CNT   3200   // 1 unsigned (barrier counter)
#define WS_XA    3264   // NSLOT*NH*DIM = 65536

// 256 blocks x 256: zero accumulators + barrier counter.
__global__ __launch_bounds__(256)
void k_init(float* __restrict__ ws) {
  const int g = blockIdx.x * 256 + threadIdx.x;  // 0..65535 == NSLOT*NH*DIM
  ws[WS_XA + g] = 0.f;
  if (g < NSLOT * NH) ws[WS_S + g]   = 0.f;
  if (g < NH * DIM)   ws[WS_QKS + g] = 0.f;
  if (g == 0) *((unsigned*)(ws + WS_CNT)) = 0u;
}

// Grid barrier: monotonic counter, phase target = phase * NBLK.
__device__ __forceinline__ void gsync(unsigned* cnt, unsigned target) {
  __syncthreads();
  if (threadIdx.x == 0) {
    __threadfence();                       // release: drain my memory ops
    atomicAdd(cnt, 1u);
    while (atomicAdd(cnt, 0u) < target) __builtin_amdgcn_s_sleep(8);
    __threadfence();                       // acquire
  }
  __syncthreads();
}

__global__ __launch_bounds__(256, 4)
void k_fused(const float* __restrict__ x, const float* __restrict__ ipw,
             const float* __restrict__ ipb, const float* __restrict__ opw,
             const float* __restrict__ opb, float* __restrict__ out,
             float* __restrict__ ws) {
  const int tid = threadIdx.x, bid = blockIdx.x;
  const int wave = tid >> 6, lane = tid & 63;
  const int T = bid + NBLK * wave;         // striped wave-task id
  unsigned* cnt = (unsigned*)(ws + WS_CNT);

  __shared__ float lds_xa[2][NH * DIM];    // 16 KB
  __shared__ float lds_s[4][NH];

  // ---- P0: q[T] = x0 . Wq[T,:] + bq[T]  (one wave per output) ----
  if (T < DIM) {
    const float4 xa = *(const float4*)(x + lane * 8);
    const float4 xb = *(const float4*)(x + lane * 8 + 4);
    const float* wr = ipw + (size_t)T * DIM + lane * 8;
    const float4 wa = *(const float4*)wr;
    const float4 wb = *(const float4*)(wr + 4);
    float acc = wa.x*xa.x + wa.y*xa.y + wa.z*xa.z + wa.w*xa.w
              + wb.x*xb.x + wb.y*xb.y + wb.z*xb.z + wb.w*xb.w;
    #pragma unroll
    for (int off = 32; off; off >>= 1) acc += __shfl_xor(acc, off, 64);
    if (lane == 0) atomicExch(ws + WS_Q + T, acc + ipb[T]);  // atomic: coherent-point write
  }
  gsync(cnt, NBLK);

  // ---- P1: qk_s[col] += scale * q[16-chunk] . Wk[16-chunk, col] ----
  if (T < 256) {
    const int o  = T & 31;                 // output chunk (64 outputs)
    const int he = T >> 5;                 // hd eighth (16 rows)
    const int h  = o >> 3;
    const int col = o * 64 + lane;
    const int dp  = col & 511;
    const float* q = ws + WS_Q + h * HDIM + he * 16;
    const float* wbase = ipw + (size_t)(DIM + h * HDIM + he * 16) * DIM + dp;
    float acc = 0.f;
    #pragma unroll
    for (int i = 0; i < 16; ++i)
      acc += q[i] * wbase[(size_t)i * DIM];
    atomicAdd(ws + WS_QKS + col, acc * SCALE);
  }
  gsync(cnt, 2 * NBLK);

  // ---- P2: main streaming pass (R9 single-pass body) ----
  {
    const bool b1 = lane & 1, b2 = lane & 2;
    const int row0 = bid * ROWS_PER_TILE + wave * ROWS_PER_WAVE;

    float qk[NH][8];
    #pragma unroll
    for (int h = 0; h < NH; ++h) {
      const float4 a = *(const float4*)(ws + WS_QKS + h * DIM + lane * 8);
      const float4 b = *(const float4*)(ws + WS_QKS + h * DIM + lane * 8 + 4);
      qk[h][0]=a.x; qk[h][1]=a.y; qk[h][2]=a.z; qk[h][3]=a.w;
      qk[h][4]=b.x; qk[h][5]=b.y; qk[h][6]=b.z; qk[h][7]=b.w;
    }

    float s = 0.f;          // denominator of head (lane&3)
    float xacc[NH][8];      // xacc[i] accumulates head (lane&3)^i
    #pragma unroll
    for (int i = 0; i < NH; ++i)
      #pragma unroll
      for (int j = 0; j < 8; ++j) xacc[i][j] = 0.f;

    const float* xp = x + (size_t)row0 * DIM + lane * 8;
    #pragma unroll
    for (int r = 0; r < ROWS_PER_WAVE; ++r) {
      const float* rp = xp + (size_t)r * DIM;
      const float4 a = *(const float4*)rp;
      const float4 b = *(const float4*)(rp + 4);
      const float xr[8] = {a.x,a.y,a.z,a.w,b.x,b.y,b.z,b.w};
      float d0=0.f,d1=0.f,d2=0.f,d3=0.f;
      #pragma unroll
      for (int j = 0; j < 8; ++j) {
        d0 += qk[0][j]*xr[j]; d1 += qk[1][j]*xr[j];
        d2 += qk[2][j]*xr[j]; d3 += qk[3][j]*xr[j];
      }
      // 4x4 transpose-reduce within 4-lane groups -> lane holds head (l&3) partial
      const float x01 = b1 ? d0 : d1;
      const float x23 = b1 ? d2 : d3;
      const float A = (b1 ? d1 : d0) + __shfl_xor(x01, 1, 64);
      const float B = (b1 ? d3 : d2) + __shfl_xor(x23, 1, 64);
      const float y = b2 ? A : B;
      float v = (b2 ? B : A) + __shfl_xor(y, 2, 64);
      v += __shfl_xor(v, 4, 64);
      v += __shfl_xor(v, 8, 64);
      v += __shfl_xor(v, 16, 64);
      v += __shfl_xor(v, 32, 64);
      const float w0 = __expf(v);               // lane's head (l&3)
      const float w1 = __shfl_xor(w0, 1, 64);
      const float w2 = __shfl_xor(w0, 2, 64);
      const float w3 = __shfl_xor(w0, 3, 64);
      s += w0;
      #pragma unroll
      for (int j = 0; j < 8; ++j) {
        xacc[0][j] += w0 * xr[j];
        xacc[1][j] += w1 * xr[j];
        xacc[2][j] += w2 * xr[j];
        xacc[3][j] += w3 * xr[j];
      }
    }

    // 2-buffer combine: waves 2,3 store; waves 0,1 add.
    const int hbase = lane & 3;
    if (wave >= 2) {
      #pragma unroll
      for (int i = 0; i < NH; ++i)
        #pragma unroll
        for (int j = 0; j < 8; ++j)
          lds_xa[wave - 2][((hbase ^ i) << 9) + lane * 8 + j] = xacc[i][j];
    }
    if (lane < NH) lds_s[wave][lane] = s;
    __syncthreads();
    if (wave < 2) {
      #pragma unroll
      for (int i = 0; i < NH; ++i)
        #pragma unroll
        for (int j = 0; j < 8; ++j)
          lds_xa[wave][((hbase ^ i) << 9) + lane * 8 + j] += xacc[i][j];
    }
    __syncthreads();

    const int slot = bid & (NSLOT - 1);
    if (tid < NH) {
      atomicAdd(ws + WS_S + slot * NH + tid,
                lds_s[0][tid] + lds_s[1][tid] + lds_s[2][tid] + lds_s[3][tid]);
    }
    #pragma unroll
    for (int j = 0; j < 8; ++j) {
      const int p = tid + 256 * j;  // 0..2047, stride-1 across lanes
      atomicAdd(ws + WS_XA + slot * (NH * DIM) + p, lds_xa[0][p] + lds_xa[1][p]);
    }
  }
  gsync(cnt, 3 * NBLK);

  // ---- P3: vproj: attn[c] = bv[c] + (Wv[c,:] . xA[h,:]) / S_h ----
  if (T < DIM) {
    const int c = T, h = c >> 7;
    float xs[8] = {0.f,0.f,0.f,0.f,0.f,0.f,0.f,0.f};
    #pragma unroll
    for (int sl = 0; sl < NSLOT; ++sl) {
      const float* xv = ws + WS_XA + sl * (NH * DIM) + h * DIM + lane * 8;
      const float4 a = *(const float4*)xv;
      const float4 b = *(const float4*)(xv + 4);
      xs[0]+=a.x; xs[1]+=a.y; xs[2]+=a.z; xs[3]+=a.w;
      xs[4]+=b.x; xs[5]+=b.y; xs[6]+=b.z; xs[7]+=b.w;
    }
    float S = 0.f;
    #pragma unroll
    for (int sl = 0; sl < NSLOT; ++sl) S += ws[WS_S + sl * NH + h];

    const float* wr = ipw + (size_t)(2 * DIM + c) * DIM + lane * 8;
    const float4 wa = *(const float4*)wr;
    const float4 wb = *(const float4*)(wr + 4);
    float acc = wa.x*xs[0] + wa.y*xs[1] + wa.z*xs[2] + wa.w*xs[3]
              + wb.x*xs[4] + wb.y*xs[5] + wb.z*xs[6] + wb.w*xs[7];
    #pragma unroll
    for (int off = 32; off; off >>= 1) acc += __shfl_xor(acc, off, 64);
    if (lane == 0)
      atomicExch(ws + WS_ATTN + c, acc / S + ipb[2 * DIM + c]);
  }
  gsync(cnt, 4 * NBLK);

  // ---- P4: oproj: out[i] = bo[i] + Wout[i,:] . attn ----
  if (T < DIM) {
    const int i = T;
    const float4 aa = *(const float4*)(ws + WS_ATTN + lane * 8);
    const float4 ab = *(const float4*)(ws + WS_ATTN + lane * 8 + 4);
    const float* wr = opw + (size_t)i * DIM + lane * 8;
    const float4 wa = *(const float4*)wr;
    const float4 wb = *(const float4*)(wr + 4);
    float acc = wa.x*aa.x + wa.y*aa.y + wa.z*aa.z + wa.w*aa.w
              + wb.x*ab.x + wb.y*ab.y + wb.z*ab.z + wb.w*ab.w;
    #pragma unroll
    for (int off = 32; off; off >>= 1) acc += __shfl_xor(acc, off, 64);
    if (lane == 0) out[i] = acc + opb[i];
  }
}

extern "C" void kernel_launch(void* const* d_in, const int* in_sizes, int n_in,
                              void* d_out, int out_size, void* d_ws, size_t ws_size,
                              hipStream_t stream) {
  const float* x   = (const float*)d_in[0];
  const float* ipw = (const float*)d_in[1];
  const float* ipb = (const float*)d_in[2];
  const float* opw = (const float*)d_in[3];
  const float* opb = (const float*)d_in[4];
  float* out = (float*)d_out;
  float* ws  = (float*)d_ws;

  k_init <<<256, 256, 0, stream>>>(ws);
  k_fused<<<NBLK, 256, 0, stream>>>(x, ipw, ipb, opw, opb, out, ws);
}